// Round 2
// baseline (3962.447 us; speedup 1.0000x reference)
//
#include <hip/hip_runtime.h>

#define B 8
#define N 16384
#define S 2048
#define NS 32
#define CIN 16

// ---------------- FPS: one block per batch ----------------
// Exact-fp32 replication of:
//   d = sum((xyz - centroid)^2, -1); min_d = min(min_d, d); nxt = argmax(min_d) (first max)
__global__ __launch_bounds__(1024, 1) void fps_kernel(const float* __restrict__ xyz,
                                                      float* __restrict__ new_xyz) {
#pragma clang fp contract(off)
    const int b = blockIdx.x;
    const int t = threadIdx.x;
    const float* xb = xyz + (size_t)b * N * 3;

    float px[16], py[16], pz[16], md[16];
#pragma unroll
    for (int k = 0; k < 16; ++k) {
        const int n = t + (k << 10);
        px[k] = xb[3 * n + 0];
        py[k] = xb[3 * n + 1];
        pz[k] = xb[3 * n + 2];
        md[k] = 1e10f;
    }

    __shared__ float rv[2][16];
    __shared__ int slot[2];
    if (t == 0) { slot[0] = 0x7fffffff; slot[1] = 0x7fffffff; }
    __syncthreads();

    int far = 0;
    int p = 0;
    const int lane = t & 63;
    const int w = t >> 6;

    for (int it = 0; it < S; ++it) {
        // centroid coords (uniform broadcast load, L2-resident)
        const float cx = xb[3 * far + 0];
        const float cy = xb[3 * far + 1];
        const float cz = xb[3 * far + 2];
        if (t == 0) {
            float* o = new_xyz + ((size_t)b * S + it) * 3;
            o[0] = cx; o[1] = cy; o[2] = cz;
        }
        float bestv = -1.0f;
#pragma unroll
        for (int k = 0; k < 16; ++k) {
            const float dx = __fsub_rn(px[k], cx);
            const float dy = __fsub_rn(py[k], cy);
            const float dz = __fsub_rn(pz[k], cz);
            const float d  = __fadd_rn(__fadd_rn(__fmul_rn(dx, dx), __fmul_rn(dy, dy)),
                                       __fmul_rn(dz, dz));
            const float m = fminf(md[k], d);
            md[k] = m;
            bestv = fmaxf(bestv, m);
        }
        // wave max
        float v = bestv;
#pragma unroll
        for (int off = 32; off >= 1; off >>= 1)
            v = fmaxf(v, __shfl_down(v, off));
        if (lane == 0) rv[p][w] = v;
        __syncthreads();
        // block max, computed redundantly in every wave (no 2nd value barrier)
        float u = rv[p][lane & 15];
#pragma unroll
        for (int off = 8; off >= 1; off >>= 1)
            u = fmaxf(u, __shfl_xor(u, off));
        // reset the other slot for the NEXT iteration (race-free: guarded by barriers)
        if (t == 0) slot[p ^ 1] = 0x7fffffff;
        // index extraction: exact equality with the (bit-exact) max; first occurrence
        if (bestv == u) {
            int cand = 0x7fffffff;
#pragma unroll
            for (int k = 0; k < 16; ++k) {
                if (md[k] == u) cand = min(cand, t + (k << 10));
            }
            atomicMin(&slot[p], cand);
        }
        __syncthreads();
        far = slot[p];
        p ^= 1;
    }
}

// ---------------- ball query + group + MLP + maxpool: one wave per query ----------------
// d2 in FLOAT64: products of fp32 inputs are exact in f64, so membership
// (d2 <= 0.1*0.1) equals ground-truth membership -- immune to fp32
// accumulation-order differences vs the harness reference.
__global__ __launch_bounds__(64, 1) void ball_mlp_kernel(
    const float* __restrict__ xyz,
    const float* __restrict__ feat,
    const float* __restrict__ W1, const float* __restrict__ b1,
    const float* __restrict__ W2, const float* __restrict__ b2,
    const float* __restrict__ W3, const float* __restrict__ b3,
    const float* __restrict__ new_xyz,
    float* __restrict__ out_feat) {
#pragma clang fp contract(off)
    const int q = blockIdx.x;          // b*S + s
    const int b = q >> 11;             // S = 2048
    const int lane = threadIdx.x;
    const float* xb = xyz + (size_t)b * N * 3;

    const double qx = (double)new_xyz[3 * q + 0];
    const double qy = (double)new_xyz[3 * q + 1];
    const double qz = (double)new_xyz[3 * q + 2];
    const double s2 = qx * qx + qy * qy + qz * qz;
    const double R2 = 0.1 * 0.1;       // == Python 0.1*0.1 = 0.010000000000000002

    __shared__ int idxbuf[NS];
    int found = 0;
    for (int base = 0; base < N; base += 64) {
        const int n = base + lane;
        const double x = (double)xb[3 * n + 0];
        const double y = (double)xb[3 * n + 1];
        const double z = (double)xb[3 * n + 2];
        const double n2 = x * x + y * y + z * z;
        const double dt = qx * x + qy * y + qz * z;
        const double d2 = (s2 + n2) - 2.0 * dt;
        const bool ok = (d2 <= R2);
        const unsigned long long msk = __ballot(ok);
        if (ok) {
            const int pos = found + (int)__popcll(msk & ((1ull << lane) - 1ull));
            if (pos < NS) idxbuf[pos] = n;
        }
        found += (int)__popcll(msk);
        if (found >= NS) break;
    }
    __syncthreads();
    if (lane == 0) {
        const int cnt = found < NS ? found : NS;
        const int first = (cnt > 0) ? idxbuf[0] : (N - 1);  // ref OOB index clips to N-1
        for (int j2 = cnt; j2 < NS; ++j2) idxbuf[j2] = first;
    }
    __syncthreads();

    // MLP: neighbor j = lane & 31 (lanes 32-63 duplicate), every lane computes all 64 out channels
    const int j = lane & 31;
    const int nid = idxbuf[j];
    const float* fp = feat + ((size_t)b * N + nid) * CIN;
    float fv[CIN];
#pragma unroll
    for (int k = 0; k < CIN; ++k) fv[k] = fp[k];

    float h1[32];
#pragma unroll
    for (int c = 0; c < 32; ++c) {
        float a = b1[c];
#pragma unroll
        for (int k = 0; k < CIN; ++k) a = fmaf(fv[k], W1[(k << 5) + c], a);
        h1[c] = fmaxf(a, 0.0f);
    }
    float h2[32];
#pragma unroll
    for (int c = 0; c < 32; ++c) {
        float a = b2[c];
#pragma unroll
        for (int k = 0; k < 32; ++k) a = fmaf(h1[k], W2[(k << 5) + c], a);
        h2[c] = fmaxf(a, 0.0f);
    }
    float mx[64];
#pragma unroll
    for (int c = 0; c < 64; ++c) {
        float a = b3[c];
#pragma unroll
        for (int k = 0; k < 32; ++k) a = fmaf(h2[k], W3[(k << 6) + c], a);
        mx[c] = a;
    }
    // max over the 32 neighbor lanes (lanes j and j+32 hold identical data)
#pragma unroll
    for (int off = 1; off <= 16; off <<= 1) {
#pragma unroll
        for (int c = 0; c < 64; ++c) mx[c] = fmaxf(mx[c], __shfl_xor(mx[c], off));
    }
    if (j == 0) {
        const int cbase = (lane >> 5) << 5;          // lane 0 -> ch 0..31, lane 32 -> ch 32..63
        float* o = out_feat + (size_t)q * 64 + cbase;
#pragma unroll
        for (int c = 0; c < 32; ++c) o[c] = mx[cbase + c];
    }
}

extern "C" void kernel_launch(void* const* d_in, const int* in_sizes, int n_in,
                              void* d_out, int out_size, void* d_ws, size_t ws_size,
                              hipStream_t stream) {
    (void)in_sizes; (void)n_in; (void)d_ws; (void)ws_size; (void)out_size;
    const float* xyz  = (const float*)d_in[0];
    const float* feat = (const float*)d_in[1];
    const float* W1   = (const float*)d_in[2];
    const float* b1   = (const float*)d_in[3];
    const float* W2   = (const float*)d_in[4];
    const float* b2   = (const float*)d_in[5];
    const float* W3   = (const float*)d_in[6];
    const float* b3   = (const float*)d_in[7];

    float* out      = (float*)d_out;
    float* new_xyz  = out;                          // B*S*3 = 49152 floats
    float* new_feat = out + (size_t)B * S * 3;      // B*S*64 floats

    fps_kernel<<<B, 1024, 0, stream>>>(xyz, new_xyz);
    ball_mlp_kernel<<<B * S, 64, 0, stream>>>(xyz, feat, W1, b1, W2, b2, W3, b3,
                                              new_xyz, new_feat);
}

// Round 3
// 3637.312 us; speedup vs baseline: 1.0894x; 1.0894x over previous
//
#include <hip/hip_runtime.h>

#define B 8
#define N 16384
#define S 2048
#define NS 32
#define CIN 16
#define NCELL 512

__device__ __forceinline__ int expand3(int v) {
    // 3-bit -> every 3rd bit
    return (v & 1) | ((v & 2) << 2) | ((v & 4) << 4);
}

// ---------------- bucket sort: morton-cell order, SoA output ----------------
__global__ __launch_bounds__(1024) void bucket_kernel(const float* __restrict__ xyz,
                                                      float* __restrict__ Xp,
                                                      float* __restrict__ Yp,
                                                      float* __restrict__ Zp,
                                                      int* __restrict__ Ip) {
    const int b = blockIdx.x;
    const int t = threadIdx.x;
    const float* xb = xyz + (size_t)b * N * 3;

    __shared__ int hist[NCELL], pA[NCELL], pB[NCELL], run[NCELL];
    if (t < NCELL) { hist[t] = 0; run[t] = 0; }
    __syncthreads();

    int cell[16];
    float xs[16], ys[16], zs[16];
#pragma unroll
    for (int k = 0; k < 16; ++k) {
        const int n = t + (k << 10);
        const float x = xb[3 * n + 0];
        const float y = xb[3 * n + 1];
        const float z = xb[3 * n + 2];
        int cx = min(7, max(0, (int)(x * 8.0f)));
        int cy = min(7, max(0, (int)(y * 8.0f)));
        int cz = min(7, max(0, (int)(z * 8.0f)));
        const int c = expand3(cx) | (expand3(cy) << 1) | (expand3(cz) << 2);
        cell[k] = c; xs[k] = x; ys[k] = y; zs[k] = z;
        atomicAdd(&hist[c], 1);
    }
    __syncthreads();

    // inclusive scan of hist (Hillis-Steele, ping-pong)
    int* cur = pA; int* nxt = pB;
    if (t < NCELL) cur[t] = hist[t];
    __syncthreads();
    for (int off = 1; off < NCELL; off <<= 1) {
        if (t < NCELL) nxt[t] = cur[t] + ((t >= off) ? cur[t - off] : 0);
        __syncthreads();
        int* tmp = cur; cur = nxt; nxt = tmp;
    }
    // exclusive base into nxt
    if (t < NCELL) nxt[t] = cur[t] - hist[t];
    __syncthreads();
    const int* base = nxt;

#pragma unroll
    for (int k = 0; k < 16; ++k) {
        const int c = cell[k];
        const int pos = base[c] + atomicAdd(&run[c], 1);
        const size_t o = (size_t)b * N + pos;
        Xp[o] = xs[k]; Yp[o] = ys[k]; Zp[o] = zs[k];
        Ip[o] = t + (k << 10);
    }
}

// ---------------- FPS on sorted SoA with exact bbox pruning ----------------
__global__ __launch_bounds__(1024) void fps_sorted_kernel(const float* __restrict__ xyz,
                                                          const float* __restrict__ Xp,
                                                          const float* __restrict__ Yp,
                                                          const float* __restrict__ Zp,
                                                          const int* __restrict__ Ip,
                                                          float* __restrict__ new_xyz) {
#pragma clang fp contract(off)
    const int b = blockIdx.x;
    const int t = threadIdx.x;
    const float* xb = xyz + (size_t)b * N * 3;
    const int l = t & 63;
    const int w = t >> 6;
    const size_t chunk = (size_t)b * N + ((size_t)w << 10) + l;

    float px[16], py[16], pz[16], md[16];
#pragma unroll
    for (int k = 0; k < 16; ++k) {
        px[k] = Xp[chunk + (k << 6)];
        py[k] = Yp[chunk + (k << 6)];
        pz[k] = Zp[chunk + (k << 6)];
        md[k] = 1e10f;
    }
    // pin coordinates in VGPRs: forbid rematerialized reloads from global
#pragma unroll
    for (int k = 0; k < 16; ++k) {
        asm volatile("" : "+v"(px[k]), "+v"(py[k]), "+v"(pz[k]));
    }

    // wave bbox (exact min/max)
    float lox = px[0], hix = px[0], loy = py[0], hiy = py[0], loz = pz[0], hiz = pz[0];
#pragma unroll
    for (int k = 1; k < 16; ++k) {
        lox = fminf(lox, px[k]); hix = fmaxf(hix, px[k]);
        loy = fminf(loy, py[k]); hiy = fmaxf(hiy, py[k]);
        loz = fminf(loz, pz[k]); hiz = fmaxf(hiz, pz[k]);
    }
#pragma unroll
    for (int off = 32; off >= 1; off >>= 1) {
        lox = fminf(lox, __shfl_xor(lox, off)); hix = fmaxf(hix, __shfl_xor(hix, off));
        loy = fminf(loy, __shfl_xor(loy, off)); hiy = fmaxf(hiy, __shfl_xor(hiy, off));
        loz = fminf(loz, __shfl_xor(loz, off)); hiz = fmaxf(hiz, __shfl_xor(hiz, off));
    }

    __shared__ float rv[2][16];
    __shared__ int slot[2];
    if (t == 0) { slot[0] = 0x7fffffff; slot[1] = 0x7fffffff; }
    __syncthreads();

    int far = 0;
    int p = 0;
    float wave_ub = 1e30f;
    float bestv = -1.0f;  // persists across skipped iterations (md unchanged -> still exact)

    for (int it = 0; it < S; ++it) {
        const float cx = xb[3 * far + 0];
        const float cy = xb[3 * far + 1];
        const float cz = xb[3 * far + 2];
        if (t == 0) {
            float* o = new_xyz + ((size_t)b * S + it) * 3;
            o[0] = cx; o[1] = cy; o[2] = cz;
        }
        // conservative lower bound of dist^2(c, wave bbox); margin >> fp32 error
        const float ddx = fmaxf(0.0f, fmaxf(lox - cx, cx - hix));
        const float ddy = fmaxf(0.0f, fmaxf(loy - cy, cy - hiy));
        const float ddz = fmaxf(0.0f, fmaxf(loz - cz, cz - hiz));
        const float lb = (ddx * ddx + ddy * ddy) + ddz * ddz;
        const bool skip = (lb * 0.99998f) > wave_ub;  // skip => min(md,d)==md for all pts, exact

        if (!skip) {
            bestv = -1.0f;
#pragma unroll
            for (int k = 0; k < 16; ++k) {
                const float dx = __fsub_rn(px[k], cx);
                const float dy = __fsub_rn(py[k], cy);
                const float dz = __fsub_rn(pz[k], cz);
                const float d  = __fadd_rn(__fadd_rn(__fmul_rn(dx, dx), __fmul_rn(dy, dy)),
                                           __fmul_rn(dz, dz));
                const float m = fminf(md[k], d);
                md[k] = m;
                bestv = fmaxf(bestv, m);
            }
        }
        // wave max (exact; all lanes receive it)
        float v = bestv;
#pragma unroll
        for (int off = 32; off >= 1; off >>= 1)
            v = fmaxf(v, __shfl_xor(v, off));
        wave_ub = v;
        if (l == 0) rv[p][w] = v;
        __syncthreads();
        // block max, redundantly in every wave
        float u = rv[p][l & 15];
#pragma unroll
        for (int off = 8; off >= 1; off >>= 1)
            u = fmaxf(u, __shfl_xor(u, off));
        if (t == 0) slot[p ^ 1] = 0x7fffffff;
        // first-occurrence (min ORIGINAL index) among md == u
        if (bestv == u) {
            int cand = 0x7fffffff;
#pragma unroll
            for (int k = 0; k < 16; ++k) {
                if (md[k] == u) cand = min(cand, Ip[chunk + (k << 6)]);
            }
            atomicMin(&slot[p], cand);
        }
        __syncthreads();
        far = slot[p];
        p ^= 1;
    }
}

// ---------------- fallback FPS (no workspace needed) ----------------
__global__ __launch_bounds__(1024) void fps_kernel(const float* __restrict__ xyz,
                                                   float* __restrict__ new_xyz) {
#pragma clang fp contract(off)
    const int b = blockIdx.x;
    const int t = threadIdx.x;
    const float* xb = xyz + (size_t)b * N * 3;

    float px[16], py[16], pz[16], md[16];
#pragma unroll
    for (int k = 0; k < 16; ++k) {
        const int n = t + (k << 10);
        px[k] = xb[3 * n + 0];
        py[k] = xb[3 * n + 1];
        pz[k] = xb[3 * n + 2];
        md[k] = 1e10f;
    }
#pragma unroll
    for (int k = 0; k < 16; ++k) {
        asm volatile("" : "+v"(px[k]), "+v"(py[k]), "+v"(pz[k]));
    }

    __shared__ float rv[2][16];
    __shared__ int slot[2];
    if (t == 0) { slot[0] = 0x7fffffff; slot[1] = 0x7fffffff; }
    __syncthreads();

    int far = 0;
    int p = 0;
    const int lane = t & 63;
    const int w = t >> 6;

    for (int it = 0; it < S; ++it) {
        const float cx = xb[3 * far + 0];
        const float cy = xb[3 * far + 1];
        const float cz = xb[3 * far + 2];
        if (t == 0) {
            float* o = new_xyz + ((size_t)b * S + it) * 3;
            o[0] = cx; o[1] = cy; o[2] = cz;
        }
        float bestv = -1.0f;
#pragma unroll
        for (int k = 0; k < 16; ++k) {
            const float dx = __fsub_rn(px[k], cx);
            const float dy = __fsub_rn(py[k], cy);
            const float dz = __fsub_rn(pz[k], cz);
            const float d  = __fadd_rn(__fadd_rn(__fmul_rn(dx, dx), __fmul_rn(dy, dy)),
                                       __fmul_rn(dz, dz));
            const float m = fminf(md[k], d);
            md[k] = m;
            bestv = fmaxf(bestv, m);
        }
        float v = bestv;
#pragma unroll
        for (int off = 32; off >= 1; off >>= 1)
            v = fmaxf(v, __shfl_xor(v, off));
        if (lane == 0) rv[p][w] = v;
        __syncthreads();
        float u = rv[p][lane & 15];
#pragma unroll
        for (int off = 8; off >= 1; off >>= 1)
            u = fmaxf(u, __shfl_xor(u, off));
        if (t == 0) slot[p ^ 1] = 0x7fffffff;
        if (bestv == u) {
            int cand = 0x7fffffff;
#pragma unroll
            for (int k = 0; k < 16; ++k) {
                if (md[k] == u) cand = min(cand, t + (k << 10));
            }
            atomicMin(&slot[p], cand);
        }
        __syncthreads();
        far = slot[p];
        p ^= 1;
    }
}

// ---------------- ball query + group + MLP + maxpool: one wave per query ----------------
__global__ __launch_bounds__(64) void ball_mlp_kernel(
    const float* __restrict__ xyz,
    const float* __restrict__ feat,
    const float* __restrict__ W1, const float* __restrict__ b1,
    const float* __restrict__ W2, const float* __restrict__ b2,
    const float* __restrict__ W3, const float* __restrict__ b3,
    const float* __restrict__ new_xyz,
    float* __restrict__ out_feat) {
#pragma clang fp contract(off)
    const int q = blockIdx.x;          // b*S + s
    const int b = q >> 11;             // S = 2048
    const int lane = threadIdx.x;
    const float* xb = xyz + (size_t)b * N * 3;

    const double qx = (double)new_xyz[3 * q + 0];
    const double qy = (double)new_xyz[3 * q + 1];
    const double qz = (double)new_xyz[3 * q + 2];
    const double s2 = qx * qx + qy * qy + qz * qz;
    const double R2 = 0.1 * 0.1;

    __shared__ int idxbuf[NS];
    int found = 0;
    for (int base = 0; base < N; base += 64) {
        const int n = base + lane;
        const double x = (double)xb[3 * n + 0];
        const double y = (double)xb[3 * n + 1];
        const double z = (double)xb[3 * n + 2];
        const double n2 = x * x + y * y + z * z;
        const double dt = qx * x + qy * y + qz * z;
        const double d2 = (s2 + n2) - 2.0 * dt;
        const bool ok = (d2 <= R2);
        const unsigned long long msk = __ballot(ok);
        if (ok) {
            const int pos = found + (int)__popcll(msk & ((1ull << lane) - 1ull));
            if (pos < NS) idxbuf[pos] = n;
        }
        found += (int)__popcll(msk);
        if (found >= NS) break;
    }
    __syncthreads();
    if (lane == 0) {
        const int cnt = found < NS ? found : NS;
        const int first = (cnt > 0) ? idxbuf[0] : (N - 1);
        for (int j2 = cnt; j2 < NS; ++j2) idxbuf[j2] = first;
    }
    __syncthreads();

    const int j = lane & 31;
    const int nid = idxbuf[j];
    const float* fp = feat + ((size_t)b * N + nid) * CIN;
    float fv[CIN];
#pragma unroll
    for (int k = 0; k < CIN; ++k) fv[k] = fp[k];

    float h1[32];
#pragma unroll
    for (int c = 0; c < 32; ++c) {
        float a = b1[c];
#pragma unroll
        for (int k = 0; k < CIN; ++k) a = fmaf(fv[k], W1[(k << 5) + c], a);
        h1[c] = fmaxf(a, 0.0f);
    }
    float h2[32];
#pragma unroll
    for (int c = 0; c < 32; ++c) {
        float a = b2[c];
#pragma unroll
        for (int k = 0; k < 32; ++k) a = fmaf(h1[k], W2[(k << 5) + c], a);
        h2[c] = fmaxf(a, 0.0f);
    }
    float mx[64];
#pragma unroll
    for (int c = 0; c < 64; ++c) {
        float a = b3[c];
#pragma unroll
        for (int k = 0; k < 32; ++k) a = fmaf(h2[k], W3[(k << 6) + c], a);
        mx[c] = a;
    }
#pragma unroll
    for (int off = 1; off <= 16; off <<= 1) {
#pragma unroll
        for (int c = 0; c < 64; ++c) mx[c] = fmaxf(mx[c], __shfl_xor(mx[c], off));
    }
    if (j == 0) {
        const int cbase = (lane >> 5) << 5;
        float* o = out_feat + (size_t)q * 64 + cbase;
#pragma unroll
        for (int c = 0; c < 32; ++c) o[c] = mx[cbase + c];
    }
}

extern "C" void kernel_launch(void* const* d_in, const int* in_sizes, int n_in,
                              void* d_out, int out_size, void* d_ws, size_t ws_size,
                              hipStream_t stream) {
    (void)in_sizes; (void)n_in; (void)out_size;
    const float* xyz  = (const float*)d_in[0];
    const float* feat = (const float*)d_in[1];
    const float* W1   = (const float*)d_in[2];
    const float* b1   = (const float*)d_in[3];
    const float* W2   = (const float*)d_in[4];
    const float* b2   = (const float*)d_in[5];
    const float* W3   = (const float*)d_in[6];
    const float* b3   = (const float*)d_in[7];

    float* out      = (float*)d_out;
    float* new_xyz  = out;                          // B*S*3 floats
    float* new_feat = out + (size_t)B * S * 3;      // B*S*64 floats

    const size_t need = (size_t)4 * B * N * sizeof(float);  // X,Y,Z,IDX SoA
    if (ws_size >= need) {
        float* Xp = (float*)d_ws;
        float* Yp = Xp + (size_t)B * N;
        float* Zp = Yp + (size_t)B * N;
        int*   Ip = (int*)(Zp + (size_t)B * N);
        bucket_kernel<<<B, 1024, 0, stream>>>(xyz, Xp, Yp, Zp, Ip);
        fps_sorted_kernel<<<B, 1024, 0, stream>>>(xyz, Xp, Yp, Zp, Ip, new_xyz);
    } else {
        fps_kernel<<<B, 1024, 0, stream>>>(xyz, new_xyz);
    }
    ball_mlp_kernel<<<B * S, 64, 0, stream>>>(xyz, feat, W1, b1, W2, b2, W3, b3,
                                              new_xyz, new_feat);
}

// Round 4
// 2412.748 us; speedup vs baseline: 1.6423x; 1.5075x over previous
//
#include <hip/hip_runtime.h>

#define B 8
#define N 16384
#define S 2048
#define NS 32
#define CIN 16
#define NCELL 512

// ---------------- DPP wave-64 reductions (all lanes must be active) ----------------
template<int CTRL>
__device__ __forceinline__ float dpp_fmax(float x) {
    int t = __builtin_amdgcn_update_dpp(0, __float_as_int(x), CTRL, 0xF, 0xF, true);
    return fmaxf(x, __int_as_float(t));
}
template<int CTRL>
__device__ __forceinline__ unsigned dpp_umax(unsigned x) {
    unsigned t = (unsigned)__builtin_amdgcn_update_dpp(0, (int)x, CTRL, 0xF, 0xF, true);
    return x > t ? x : t;
}
// quad_perm[1,0,3,2]=0xB1, quad_perm[2,3,0,1]=0x4E, row_shr:4=0x114, row_shr:8=0x118,
// row_bcast15=0x142, row_bcast31=0x143  -> lane 63 holds the wave max; identity = 0 (values >= 0)
__device__ __forceinline__ float wave_fmax(float x) {
    x = dpp_fmax<0xB1>(x);
    x = dpp_fmax<0x4E>(x);
    x = dpp_fmax<0x114>(x);
    x = dpp_fmax<0x118>(x);
    x = dpp_fmax<0x142>(x);
    x = dpp_fmax<0x143>(x);
    return __int_as_float(__builtin_amdgcn_readlane(__float_as_int(x), 63));
}
__device__ __forceinline__ unsigned wave_umax(unsigned x) {
    x = dpp_umax<0xB1>(x);
    x = dpp_umax<0x4E>(x);
    x = dpp_umax<0x114>(x);
    x = dpp_umax<0x118>(x);
    x = dpp_umax<0x142>(x);
    x = dpp_umax<0x143>(x);
    return (unsigned)__builtin_amdgcn_readlane((int)x, 63);
}

__device__ __forceinline__ int expand3(int v) {
    return (v & 1) | ((v & 2) << 2) | ((v & 4) << 4);
}

// ---------------- bucket sort: morton-cell order, SoA output ----------------
__global__ __launch_bounds__(1024) void bucket_kernel(const float* __restrict__ xyz,
                                                      float* __restrict__ Xp,
                                                      float* __restrict__ Yp,
                                                      float* __restrict__ Zp,
                                                      int* __restrict__ Ip) {
    const int b = blockIdx.x;
    const int t = threadIdx.x;
    const float* xb = xyz + (size_t)b * N * 3;

    __shared__ int hist[NCELL], pA[NCELL], pB[NCELL], run[NCELL];
    if (t < NCELL) { hist[t] = 0; run[t] = 0; }
    __syncthreads();

    int cell[16];
    float xs[16], ys[16], zs[16];
#pragma unroll
    for (int k = 0; k < 16; ++k) {
        const int n = t + (k << 10);
        const float x = xb[3 * n + 0];
        const float y = xb[3 * n + 1];
        const float z = xb[3 * n + 2];
        int cx = min(7, max(0, (int)(x * 8.0f)));
        int cy = min(7, max(0, (int)(y * 8.0f)));
        int cz = min(7, max(0, (int)(z * 8.0f)));
        const int c = expand3(cx) | (expand3(cy) << 1) | (expand3(cz) << 2);
        cell[k] = c; xs[k] = x; ys[k] = y; zs[k] = z;
        atomicAdd(&hist[c], 1);
    }
    __syncthreads();

    int* cur = pA; int* nxt = pB;
    if (t < NCELL) cur[t] = hist[t];
    __syncthreads();
    for (int off = 1; off < NCELL; off <<= 1) {
        if (t < NCELL) nxt[t] = cur[t] + ((t >= off) ? cur[t - off] : 0);
        __syncthreads();
        int* tmp = cur; cur = nxt; nxt = tmp;
    }
    if (t < NCELL) nxt[t] = cur[t] - hist[t];
    __syncthreads();
    const int* base = nxt;

#pragma unroll
    for (int k = 0; k < 16; ++k) {
        const int c = cell[k];
        const int pos = base[c] + atomicAdd(&run[c], 1);
        const size_t o = (size_t)b * N + pos;
        Xp[o] = xs[k]; Yp[o] = ys[k]; Zp[o] = zs[k];
        Ip[o] = t + (k << 10);
    }
}

// ---------------- FPS: per-thread 16-pt bbox prune, DPP reduce, 1 barrier/iter ----------------
__global__ __launch_bounds__(1024, 1) void fps_prune_kernel(const float* __restrict__ xyz,
                                                            const float* __restrict__ Xp,
                                                            const float* __restrict__ Yp,
                                                            const float* __restrict__ Zp,
                                                            const int* __restrict__ Ip,
                                                            float* __restrict__ new_xyz) {
#pragma clang fp contract(off)
    const int b = blockIdx.x;
    const int t = threadIdx.x;
    const float* xb = xyz + (size_t)b * N * 3;
    const size_t base = (size_t)b * N + ((size_t)t << 4);   // 16 consecutive sorted pts

    float px[16], py[16], pz[16], md[16];
    int ip[16];
#pragma unroll
    for (int k = 0; k < 16; ++k) {
        px[k] = Xp[base + k];
        py[k] = Yp[base + k];
        pz[k] = Zp[base + k];
        ip[k] = Ip[base + k];
        md[k] = 1e10f;
    }
    // pin: forbids rematerialized global reloads (compiler can't prove equivalence)
#pragma unroll
    for (int k = 0; k < 16; ++k) {
        asm volatile("" : "+v"(px[k]), "+v"(py[k]), "+v"(pz[k]), "+v"(ip[k]));
    }

    // per-thread bbox (tight: points are Morton-adjacent)
    float lox = px[0], hix = px[0], loy = py[0], hiy = py[0], loz = pz[0], hiz = pz[0];
#pragma unroll
    for (int k = 1; k < 16; ++k) {
        lox = fminf(lox, px[k]); hix = fmaxf(hix, px[k]);
        loy = fminf(loy, py[k]); hiy = fmaxf(hiy, py[k]);
        loz = fminf(loz, pz[k]); hiz = fmaxf(hiz, pz[k]);
    }

    __shared__ unsigned long long slot3[3];
    if (t == 0) { slot3[0] = 0ull; slot3[1] = 0ull; slot3[2] = 0ull; }
    __syncthreads();

    int far = 0;
    int p = 0;
    float ub = 1e10f;          // max over this thread's md  (>= 0 always)
    int cand = ip[0];          // min orig idx among md[k]==ub (valid once first update runs)

    for (int it = 0; it < S; ++it) {
        const float cx = xb[3 * far + 0];
        const float cy = xb[3 * far + 1];
        const float cz = xb[3 * far + 2];
        if (t == 0) {
            float* o = new_xyz + ((size_t)b * S + it) * 3;
            o[0] = cx; o[1] = cy; o[2] = cz;
        }
        // exact conservative skip: lb*(1-2e-5) > ub  =>  d_fp32 > md for all 16 pts
        const float ddx = fmaxf(0.0f, fmaxf(lox - cx, cx - hix));
        const float ddy = fmaxf(0.0f, fmaxf(loy - cy, cy - hiy));
        const float ddz = fmaxf(0.0f, fmaxf(loz - cz, cz - hiz));
        const float lb = (ddx * ddx + ddy * ddy) + ddz * ddz;

        if (!(lb * 0.99998f > ub)) {
            float nu = 0.0f;
#pragma unroll
            for (int k = 0; k < 16; ++k) {
                const float dx = __fsub_rn(px[k], cx);
                const float dy = __fsub_rn(py[k], cy);
                const float dz = __fsub_rn(pz[k], cz);
                const float d  = __fadd_rn(__fadd_rn(__fmul_rn(dx, dx), __fmul_rn(dy, dy)),
                                           __fmul_rn(dz, dz));
                const float m = fminf(md[k], d);
                md[k] = m;
                nu = fmaxf(nu, m);
            }
            int c = 0x7fffffff;
#pragma unroll
            for (int k = 0; k < 16; ++k) {
                if (md[k] == nu) c = min(c, ip[k]);
            }
            ub = nu; cand = c;
        }
        // wave reduce: (max ub) then (min orig idx among ties) -- all via DPP
        const float wmax = wave_fmax(ub);
        unsigned cn = (ub == wmax) ? ~(unsigned)cand : 0u;
        cn = wave_umax(cn);
        if ((t & 63) == 0) {
            atomicMax(&slot3[p],
                      ((unsigned long long)__float_as_uint(wmax) << 32) | (unsigned long long)cn);
        }
        int pn = p + 1; if (pn == 3) pn = 0;
        // reset the slot for iteration it+1; its last readers finished before barrier_{it-1}
        if (t == 0) slot3[pn] = 0ull;
        __syncthreads();
        const unsigned long long r = slot3[p];
        far = (int)(~(unsigned)r);
        p = pn;
    }
}

// ---------------- fallback FPS (no workspace) ----------------
__global__ __launch_bounds__(1024) void fps_kernel(const float* __restrict__ xyz,
                                                   float* __restrict__ new_xyz) {
#pragma clang fp contract(off)
    const int b = blockIdx.x;
    const int t = threadIdx.x;
    const float* xb = xyz + (size_t)b * N * 3;

    float px[16], py[16], pz[16], md[16];
#pragma unroll
    for (int k = 0; k < 16; ++k) {
        const int n = t + (k << 10);
        px[k] = xb[3 * n + 0];
        py[k] = xb[3 * n + 1];
        pz[k] = xb[3 * n + 2];
        md[k] = 1e10f;
    }
    __shared__ float rv[2][16];
    __shared__ int slot[2];
    if (t == 0) { slot[0] = 0x7fffffff; slot[1] = 0x7fffffff; }
    __syncthreads();
    int far = 0, p = 0;
    const int lane = t & 63, w = t >> 6;
    for (int it = 0; it < S; ++it) {
        const float cx = xb[3 * far + 0], cy = xb[3 * far + 1], cz = xb[3 * far + 2];
        if (t == 0) {
            float* o = new_xyz + ((size_t)b * S + it) * 3;
            o[0] = cx; o[1] = cy; o[2] = cz;
        }
        float bestv = -1.0f;
#pragma unroll
        for (int k = 0; k < 16; ++k) {
            const float dx = __fsub_rn(px[k], cx);
            const float dy = __fsub_rn(py[k], cy);
            const float dz = __fsub_rn(pz[k], cz);
            const float d  = __fadd_rn(__fadd_rn(__fmul_rn(dx, dx), __fmul_rn(dy, dy)),
                                       __fmul_rn(dz, dz));
            const float m = fminf(md[k], d);
            md[k] = m;
            bestv = fmaxf(bestv, m);
        }
        float v = bestv;
#pragma unroll
        for (int off = 32; off >= 1; off >>= 1) v = fmaxf(v, __shfl_xor(v, off));
        if (lane == 0) rv[p][w] = v;
        __syncthreads();
        float u = rv[p][lane & 15];
#pragma unroll
        for (int off = 8; off >= 1; off >>= 1) u = fmaxf(u, __shfl_xor(u, off));
        if (t == 0) slot[p ^ 1] = 0x7fffffff;
        if (bestv == u) {
            int cnd2 = 0x7fffffff;
#pragma unroll
            for (int k = 0; k < 16; ++k)
                if (md[k] == u) cnd2 = min(cnd2, t + (k << 10));
            atomicMin(&slot[p], cnd2);
        }
        __syncthreads();
        far = slot[p];
        p ^= 1;
    }
}

// ---------------- ball query + group + MLP + maxpool: one wave per query ----------------
// lanes = 32 neighbors x 2 channel-halves
__global__ __launch_bounds__(64) void ball_mlp_kernel(
    const float* __restrict__ xyz,
    const float* __restrict__ feat,
    const float* __restrict__ W1, const float* __restrict__ b1,
    const float* __restrict__ W2, const float* __restrict__ b2,
    const float* __restrict__ W3, const float* __restrict__ b3,
    const float* __restrict__ new_xyz,
    float* __restrict__ out_feat) {
#pragma clang fp contract(off)
    const int q = blockIdx.x;          // b*S + s
    const int b = q >> 11;             // S = 2048
    const int lane = threadIdx.x;
    const float* xb = xyz + (size_t)b * N * 3;

    const double qx = (double)new_xyz[3 * q + 0];
    const double qy = (double)new_xyz[3 * q + 1];
    const double qz = (double)new_xyz[3 * q + 2];
    const double s2 = qx * qx + qy * qy + qz * qz;
    const double R2 = 0.1 * 0.1;

    __shared__ int idxbuf[NS];
    int found = 0;
    for (int bs = 0; bs < N; bs += 64) {
        const int n = bs + lane;
        const double x = (double)xb[3 * n + 0];
        const double y = (double)xb[3 * n + 1];
        const double z = (double)xb[3 * n + 2];
        const double n2 = x * x + y * y + z * z;
        const double dt = qx * x + qy * y + qz * z;
        const double d2 = (s2 + n2) - 2.0 * dt;
        const bool ok = (d2 <= R2);
        const unsigned long long msk = __ballot(ok);
        if (ok) {
            const int pos = found + (int)__popcll(msk & ((1ull << lane) - 1ull));
            if (pos < NS) idxbuf[pos] = n;
        }
        found += (int)__popcll(msk);
        if (found >= NS) break;
    }
    __syncthreads();
    if (lane == 0) {
        const int cnt = found < NS ? found : NS;
        const int first = (cnt > 0) ? idxbuf[0] : (N - 1);
        for (int j2 = cnt; j2 < NS; ++j2) idxbuf[j2] = first;
    }
    __syncthreads();

    const int j = lane & 31;           // neighbor
    const int h = lane >> 5;           // channel half: 0 -> ch 0..31, 1 -> ch 32..63
    const int nid = idxbuf[j];
    const float* fp = feat + ((size_t)b * N + nid) * CIN;
    float fv[CIN];
#pragma unroll
    for (int k = 0; k < CIN; ++k) fv[k] = fp[k];

    float h1[32];
#pragma unroll
    for (int c = 0; c < 32; ++c) {
        float a = b1[c];
#pragma unroll
        for (int k = 0; k < CIN; ++k) a = fmaf(fv[k], W1[(k << 5) + c], a);
        h1[c] = fmaxf(a, 0.0f);
    }
    float h2[32];
#pragma unroll
    for (int c = 0; c < 32; ++c) {
        float a = b2[c];
#pragma unroll
        for (int k = 0; k < 32; ++k) a = fmaf(h1[k], W2[(k << 5) + c], a);
        h2[c] = fmaxf(a, 0.0f);
    }
    const int cbase = h << 5;
    float mx[32];
#pragma unroll
    for (int c = 0; c < 32; ++c) {
        float a = b3[cbase + c];
#pragma unroll
        for (int k = 0; k < 32; ++k) a = fmaf(h2[k], W3[(k << 6) + cbase + c], a);
        mx[c] = a;
    }
    // max over the 32 neighbors within each 32-lane half (xor stays in-half)
#pragma unroll
    for (int off = 1; off <= 16; off <<= 1) {
#pragma unroll
        for (int c = 0; c < 32; ++c) mx[c] = fmaxf(mx[c], __shfl_xor(mx[c], off));
    }
    if (j == 0) {
        float* o = out_feat + (size_t)q * 64 + cbase;
#pragma unroll
        for (int c = 0; c < 32; ++c) o[c] = mx[c];
    }
}

extern "C" void kernel_launch(void* const* d_in, const int* in_sizes, int n_in,
                              void* d_out, int out_size, void* d_ws, size_t ws_size,
                              hipStream_t stream) {
    (void)in_sizes; (void)n_in; (void)out_size;
    const float* xyz  = (const float*)d_in[0];
    const float* feat = (const float*)d_in[1];
    const float* W1   = (const float*)d_in[2];
    const float* b1   = (const float*)d_in[3];
    const float* W2   = (const float*)d_in[4];
    const float* b2   = (const float*)d_in[5];
    const float* W3   = (const float*)d_in[6];
    const float* b3   = (const float*)d_in[7];

    float* out      = (float*)d_out;
    float* new_xyz  = out;                          // B*S*3 floats
    float* new_feat = out + (size_t)B * S * 3;      // B*S*64 floats

    const size_t need = (size_t)4 * B * N * sizeof(float);
    if (ws_size >= need) {
        float* Xp = (float*)d_ws;
        float* Yp = Xp + (size_t)B * N;
        float* Zp = Yp + (size_t)B * N;
        int*   Ip = (int*)(Zp + (size_t)B * N);
        bucket_kernel<<<B, 1024, 0, stream>>>(xyz, Xp, Yp, Zp, Ip);
        fps_prune_kernel<<<B, 1024, 0, stream>>>(xyz, Xp, Yp, Zp, Ip, new_xyz);
    } else {
        fps_kernel<<<B, 1024, 0, stream>>>(xyz, new_xyz);
    }
    ball_mlp_kernel<<<B * S, 64, 0, stream>>>(xyz, feat, W1, b1, W2, b2, W3, b3,
                                              new_xyz, new_feat);
}